// Round 2
// baseline (21202.798 us; speedup 1.0000x reference)
//
#include <hip/hip_runtime.h>
#include <cstdint>
#include <cstddef>

// ---- problem constants ----
#define TT 512
#define BB 256
#define HID 768
#define INDIM 129
#define OUTD 128
#define XSTR 168   // LDS row stride (elems) for x tile, mult of 8
#define GSTR 97    // LDS row stride (f32) for gate partials, odd -> conflict-free
#define KS_TOT 58  // 48 recurrent k-steps (K=768/16) + 10 input k-steps (K=160/16)
#define KS_REC 48

typedef __attribute__((ext_vector_type(8))) short bf16x8;
typedef __attribute__((ext_vector_type(16))) float f32x16;
typedef unsigned short u16;

#define MFMA32(A, B, C) __builtin_amdgcn_mfma_f32_32x32x16_bf16(A, B, C, 0, 0, 0)
#define ZERO16 {0.f,0.f,0.f,0.f,0.f,0.f,0.f,0.f,0.f,0.f,0.f,0.f,0.f,0.f,0.f,0.f}

__device__ __forceinline__ u16 f2bf(float f) {
  union { float f; unsigned u; } v; v.f = f;
  unsigned u = v.u;
  u += 0x7fffu + ((u >> 16) & 1u);   // RNE
  return (u16)(u >> 16);
}
__device__ __forceinline__ float sigm(float x) { return 1.0f / (1.0f + __expf(-x)); }
__device__ __forceinline__ float tanh_fast(float x) { return 2.0f / (1.0f + __expf(-2.0f * x)) - 1.0f; }

// ---------------- prep: pack weights for register preload, fuse bias, zero state ----------------
__global__ __launch_bounds__(256) void prep_kernel(
    const float* __restrict__ W_ih, const float* __restrict__ W_hh,
    const float* __restrict__ b_ih, const float* __restrict__ b_hh,
    const float* __restrict__ W_dec,
    u16* __restrict__ Wpack, u16* __restrict__ Wdpack,
    float* __restrict__ biasg, u16* __restrict__ h0, unsigned* __restrict__ flags) {
  const int stride = blockDim.x * gridDim.x;
  const int i0 = blockIdx.x * blockDim.x + threadIdx.x;

  // Wpack[ct][nt][ks][lane][8]: B-frag layout for mfma_32x32x16 (n=lane&31, k=(lane>>5)*8+jj)
  for (int i = i0; i < 32 * 3 * KS_TOT * 512; i += stride) {
    int jj = i & 7, lane = (i >> 3) & 63, r = i >> 9;
    int ks = r % KS_TOT; int r2 = r / KS_TOT;
    int nt = r2 % 3, ct = r2 / 3;
    int p = nt * 32 + (lane & 31);          // packed gate-col 0..95
    int g = p / 24, j = p - g * 24;
    int row = g * HID + ct * 24 + j;        // W gate-row
    int kh = (lane >> 5) * 8 + jj;
    float v;
    if (ks < KS_REC) v = W_hh[(size_t)row * HID + ks * 16 + kh];
    else { int d = (ks - KS_REC) * 16 + kh; v = (d < INDIM) ? W_ih[(size_t)row * INDIM + d] : 0.f; }
    Wpack[i] = f2bf(v);
  }
  // Wdpack[nt][ks][lane][8]
  for (int i = i0; i < 4 * 48 * 512; i += stride) {
    int jj = i & 7, lane = (i >> 3) & 63, r = i >> 9;
    int ks = r % 48, nt = r / 48;
    int orow = nt * 32 + (lane & 31);
    int k = ks * 16 + (lane >> 5) * 8 + jj;
    Wdpack[i] = f2bf(W_dec[(size_t)orow * HID + k]);
  }
  for (int i = i0; i < 4 * HID; i += stride) biasg[i] = b_ih[i] + b_hh[i];
  for (int i = i0; i < BB * HID; i += stride) h0[i] = (u16)0;
  for (int i = i0; i < 256; i += stride) flags[i] = 0u;
}

// ---------------- persistent LSTM ----------------
__device__ __forceinline__ void waitflags(unsigned* fl, unsigned target, int l5) {
  for (;;) {
    unsigned v = __hip_atomic_load(&fl[l5], __ATOMIC_RELAXED, __HIP_MEMORY_SCOPE_AGENT);
    if (__all((int)(v >= target))) break;
    __builtin_amdgcn_s_sleep(1);
  }
  __threadfence();  // acquire: invalidate L1 so h reads are fresh
}

__device__ __forceinline__ void decode_store(
    const u16* __restrict__ h, const u16* __restrict__ Wd, float* __restrict__ out,
    int s, int b0, int ct, int lane, float bdv) {
  const int l5 = lane & 31, hi = lane >> 5;
  f32x16 acc = ZERO16;
  #pragma unroll
  for (int t = 0; t < 48; ++t) {
    bf16x8 a = *(const bf16x8*)(h + (size_t)(b0 + l5) * HID + t * 16 + hi * 8);
    bf16x8 b = *(const bf16x8*)(Wd + (((size_t)(ct - 28) * 48 + t) * 64 + lane) * 8);
    acc = MFMA32(a, b, acc);
  }
  float* ob = out + ((size_t)(s - 257) * BB + b0) * OUTD + (ct - 28) * 32;
  #pragma unroll
  for (int r = 0; r < 16; ++r) {
    int row = (r & 3) + 8 * (r >> 2) + 4 * hi;
    ob[(size_t)row * OUTD + l5] = acc[r] + bdv;
  }
}

__global__ __launch_bounds__(256, 1) void lstm_persist(
    const float* __restrict__ seq, const u16* __restrict__ Wpack,
    const u16* __restrict__ Wdpack, const float* __restrict__ biasg,
    const float* __restrict__ bdec, u16* __restrict__ hb0,
    u16* __restrict__ hb1, unsigned* __restrict__ flags,
    float* __restrict__ out) {
  __shared__ u16 xlds[2][32 * XSTR];     // 21.0 KB: x_t double buffer (bf16, zero-padded K)
  __shared__ float gbuf[3][32 * GSTR];   // 36.4 KB: per-wave gate partials
  __shared__ float cl[32 * 25];          //  3.1 KB: cell state (fp32), stride 25 = conflict-free
  __shared__ float biasl[96];
  __shared__ float big_pad[5120];        // 20 KB pad -> LDS 82.8 KB -> hard 1 WG/CU (co-residency)

  const int tid = threadIdx.x;
  const int w = tid >> 6;
  const int lane = tid & 63;
  const int l5 = lane & 31;
  const int hi = lane >> 5;
  const int bid = blockIdx.x;
  const int bt = bid >> 5;               // 0..7  batch tile (32 rows)
  const int ct = bid & 31;               // 0..31 h-col tile (24 cols)
  const int b0 = bt * 32;
  unsigned* fl = flags + bt * 32;

  // keep big_pad alive (runtime-false, workgroup-uniform guard)
  if ((const void*)seq == (const void*)flags) {
    big_pad[tid] = bdec[tid & 31]; __syncthreads(); out[tid] = big_pad[255 - tid];
  }

  for (int i = tid; i < 2 * 32 * XSTR; i += 256) ((u16*)xlds)[i] = (u16)0;
  for (int i = tid; i < 32 * 25; i += 256) cl[i] = 0.f;
  if (tid < 96) biasl[tid] = biasg[(tid / 24) * HID + ct * 24 + (tid % 24)];

  u16* hb[2] = {hb0, hb1};

  // ---- preload this wave's B fragments (Whh + Wih) into registers, once ----
  const int kbase = w * 20;
  const int nks = (w == 2) ? 18 : 20;    // 20+20+18 = 58 k-steps of 16
  bf16x8 Breg[3][20];
  if (w < 3) {
    #pragma unroll
    for (int t = 0; t < 20; ++t)
      if (t < nks) {
        #pragma unroll
        for (int nt = 0; nt < 3; ++nt)
          Breg[nt][t] = *(const bf16x8*)(Wpack +
              ((((size_t)ct * 3 + nt) * KS_TOT + (kbase + t)) * 64 + lane) * 8);
      }
  }
  const bool DEC = (ct >= 28);
  float bdv = 0.f;
  if (w == 3 && DEC) bdv = bdec[(ct - 28) * 32 + l5];

  // stage x_0
  if (w == 3) {
    const float* xs = seq + (size_t)b0 * INDIM;
    for (int i = lane; i < 32 * INDIM; i += 64) {
      int r = i / INDIM, d = i - r * INDIM;
      xlds[0][r * XSTR + d] = f2bf(xs[i]);
    }
  }
  __syncthreads();

  for (int s = 0; s < TT; ++s) {
    const u16* hprev = hb[s & 1];
    if (w == 3) {
      if (s + 1 < TT) {   // stage x_{s+1} (no dependency on h)
        const float* xs = seq + ((size_t)(s + 1) * BB + b0) * INDIM;
        u16* xd = xlds[(s + 1) & 1];
        for (int i = lane; i < 32 * INDIM; i += 64) {
          int r = i / INDIM, d = i - r * INDIM;
          xd[r * XSTR + d] = f2bf(xs[i]);
        }
      }
      if (DEC && s >= 257) {  // fused decode of h_{s-1} -> out[s-257]
        waitflags(fl, (unsigned)s, l5);
        decode_store(hprev, Wdpack, out, s, b0, ct, lane, bdv);
      }
    } else {
      // ---- recurrent + input GEMM, this wave's K-chunk, B from registers ----
      waitflags(fl, (unsigned)s, l5);
      f32x16 acc0 = ZERO16, acc1 = ZERO16, acc2 = ZERO16;
      const u16* xrow = &xlds[s & 1][l5 * XSTR + hi * 8];
      const u16* hrow = hprev + (size_t)(b0 + l5) * HID + hi * 8;
      #pragma unroll
      for (int t = 0; t < 20; ++t)
        if (t < nks) {
          const int ks = kbase + t;
          bf16x8 afrag;
          if (ks < KS_REC) afrag = *(const bf16x8*)(hrow + ks * 16);
          else             afrag = *(const bf16x8*)(xrow + (ks - KS_REC) * 16);
          acc0 = MFMA32(afrag, Breg[0][t], acc0);
          acc1 = MFMA32(afrag, Breg[1][t], acc1);
          acc2 = MFMA32(afrag, Breg[2][t], acc2);
        }
      float* gb = gbuf[w];
      #pragma unroll
      for (int r = 0; r < 16; ++r) {
        int row = (r & 3) + 8 * (r >> 2) + 4 * hi;
        gb[row * GSTR + 0 * 32 + l5] = acc0[r];
        gb[row * GSTR + 1 * 32 + l5] = acc1[r];
        gb[row * GSTR + 2 * 32 + l5] = acc2[r];
      }
    }
    __syncthreads();   // #1: gate partials + staged x + decode complete

    {  // ---- cell update: 3 cells/thread ----
      const int b = tid & 31;
      const int j0 = (tid >> 5) * 3;
      u16* hn = hb[(s + 1) & 1];
      #pragma unroll
      for (int e = 0; e < 3; ++e) {
        int j = j0 + e;
        float vi = gbuf[0][b * GSTR + j]      + gbuf[1][b * GSTR + j]      + gbuf[2][b * GSTR + j]      + biasl[j];
        float vf = gbuf[0][b * GSTR + 24 + j] + gbuf[1][b * GSTR + 24 + j] + gbuf[2][b * GSTR + 24 + j] + biasl[24 + j];
        float vg = gbuf[0][b * GSTR + 48 + j] + gbuf[1][b * GSTR + 48 + j] + gbuf[2][b * GSTR + 48 + j] + biasl[48 + j];
        float vo = gbuf[0][b * GSTR + 72 + j] + gbuf[1][b * GSTR + 72 + j] + gbuf[2][b * GSTR + 72 + j] + biasl[72 + j];
        float iv = sigm(vi), fv = sigm(vf), gv = tanh_fast(vg), ov = sigm(vo);
        float cn = fv * cl[b * 25 + j] + iv * gv;
        cl[b * 25 + j] = cn;
        hn[(size_t)(b0 + b) * HID + ct * 24 + j] = f2bf(ov * tanh_fast(cn));
      }
    }
    __syncthreads();   // #2: all h stores drained (vmcnt0 before barrier)

    if (tid == 0) {
      __threadfence();  // release: write back L2 so other XCDs see h
      __hip_atomic_store(&fl[ct], (unsigned)(s + 1), __ATOMIC_RELEASE, __HIP_MEMORY_SCOPE_AGENT);
    }
  }

  // tail: decode h_511 -> out[255]
  if (w == 3 && DEC) {
    waitflags(fl, (unsigned)TT, l5);
    decode_store(hb[0], Wdpack, out, TT, b0, ct, lane, bdv);
  }
}

extern "C" void kernel_launch(void* const* d_in, const int* in_sizes, int n_in,
                              void* d_out, int out_size, void* d_ws, size_t ws_size,
                              hipStream_t stream) {
  (void)in_sizes; (void)n_in; (void)out_size; (void)ws_size;
  const float* seq   = (const float*)d_in[0];
  const float* W_ih  = (const float*)d_in[1];
  const float* W_hh  = (const float*)d_in[2];
  const float* b_ih  = (const float*)d_in[3];
  const float* b_hh  = (const float*)d_in[4];
  const float* W_dec = (const float*)d_in[5];
  const float* b_dec = (const float*)d_in[6];
  float* out = (float*)d_out;

  // workspace layout (~6.7 MB)
  u16* Wpack  = (u16*)d_ws;                         // 32*3*58*512 = 2,850,816 bf16
  u16* Wdpack = Wpack + 32 * 3 * KS_TOT * 512;      // 4*48*512 = 98,304 bf16
  u16* h0     = Wdpack + 4 * 48 * 512;              // 256*768 bf16
  u16* h1     = h0 + BB * HID;                      // 256*768 bf16
  float* biasg = (float*)(h1 + BB * HID);           // 3072 f32
  unsigned* flags = (unsigned*)(biasg + 4 * HID);   // 256 u32 (8 bt x 32 ct)

  prep_kernel<<<512, 256, 0, stream>>>(W_ih, W_hh, b_ih, b_hh, W_dec,
                                       Wpack, Wdpack, biasg, h0, flags);
  lstm_persist<<<256, 256, 0, stream>>>(seq, Wpack, Wdpack, biasg, b_dec,
                                        h0, h1, flags, out);
}

// Round 3
// 7549.704 us; speedup vs baseline: 2.8084x; 2.8084x over previous
//
#include <hip/hip_runtime.h>
#include <cstdint>
#include <cstddef>

// ---- problem constants ----
#define TT 512
#define BB 256
#define HID 768
#define INDIM 129
#define INPAD 160
#define OUTD 128
#define KS_TOT 58   // 48 recurrent + 10 input ksteps of 16
#define KS_REC 48
#define HSTR 776    // hstage row stride (bf16): 768+8, 16B-aligned rows
#define XSTR 168    // xlds row stride (bf16)
#define GSTR 100    // gbuf row stride (f32), 16B-aligned, conflict-light

typedef __attribute__((ext_vector_type(8))) short bf16x8;
typedef __attribute__((ext_vector_type(4))) float f32x4;
typedef __attribute__((ext_vector_type(16))) float f32x16;
typedef unsigned short u16;
typedef unsigned long long u64;

#define MFMA32(A, B, C) __builtin_amdgcn_mfma_f32_32x32x16_bf16(A, B, C, 0, 0, 0)
#define ZERO16 {0.f,0.f,0.f,0.f,0.f,0.f,0.f,0.f,0.f,0.f,0.f,0.f,0.f,0.f,0.f,0.f}

__device__ __forceinline__ u16 f2bf(float f) {
  union { float f; unsigned u; } v; v.f = f;
  unsigned u = v.u;
  u += 0x7fffu + ((u >> 16) & 1u);   // RNE
  return (u16)(u >> 16);
}
__device__ __forceinline__ float sigm(float x) { return 1.0f / (1.0f + __expf(-x)); }
__device__ __forceinline__ float tanh_fast(float x) { return 2.0f / (1.0f + __expf(-2.0f * x)) - 1.0f; }

// ---------------- prep ----------------
__global__ __launch_bounds__(256) void prep_kernel(
    const float* __restrict__ W_ih, const float* __restrict__ W_hh,
    const float* __restrict__ b_ih, const float* __restrict__ b_hh,
    const float* __restrict__ W_dec, const float* __restrict__ b_dec,
    u16* __restrict__ Wpack, u16* __restrict__ Wdpack,
    float* __restrict__ biasg, u16* __restrict__ h0,
    unsigned* __restrict__ flags, float* __restrict__ out) {
  const int stride = blockDim.x * gridDim.x;
  const int i0 = blockIdx.x * blockDim.x + threadIdx.x;

  // Wpack[ct][nt][ks][lane][8]: B-frag for mfma_32x32x16 (n=lane&31, k=(lane>>5)*8+jj)
  for (int i = i0; i < 32 * 3 * KS_TOT * 512; i += stride) {
    int jj = i & 7, lane = (i >> 3) & 63, r = i >> 9;
    int ks = r % KS_TOT; int r2 = r / KS_TOT;
    int nt = r2 % 3, ct = r2 / 3;
    int p = nt * 32 + (lane & 31);          // packed gate-col 0..95
    int g = p / 24, j = p - g * 24;
    int row = g * HID + ct * 24 + j;        // W gate-row
    int kh = (lane >> 5) * 8 + jj;
    float v;
    if (ks < KS_REC) v = W_hh[(size_t)row * HID + ks * 16 + kh];
    else { int d = (ks - KS_REC) * 16 + kh; v = (d < INDIM) ? W_ih[(size_t)row * INDIM + d] : 0.f; }
    Wpack[i] = f2bf(v);
  }
  // Wdpack[ont][ks][lane][8]
  for (int i = i0; i < 4 * 48 * 512; i += stride) {
    int jj = i & 7, lane = (i >> 3) & 63, r = i >> 9;
    int ks = r % 48, nt = r / 48;
    int orow = nt * 32 + (lane & 31);
    int k = ks * 16 + (lane >> 5) * 8 + jj;
    Wdpack[i] = f2bf(W_dec[(size_t)orow * HID + k]);
  }
  for (int i = i0; i < 4 * HID; i += stride) biasg[i] = b_ih[i] + b_hh[i];
  for (int i = i0; i < BB * HID; i += stride) h0[i] = (u16)0;
  for (int i = i0; i < 256; i += stride) flags[i] = 0u;
  // out pre-init with decoder bias (decode K-split accumulates via atomicAdd)
  for (int i = i0; i < 256 * BB * OUTD; i += stride) out[i] = b_dec[i & (OUTD - 1)];
}

// ---------------- persistent LSTM ----------------
__device__ __forceinline__ void waitflags(unsigned* fl, unsigned target, int lane) {
  for (;;) {
    unsigned v = __hip_atomic_load(&fl[lane & 31], __ATOMIC_RELAXED, __HIP_MEMORY_SCOPE_AGENT);
    if (__all((int)(v >= target))) break;
    __builtin_amdgcn_s_sleep(1);
  }
  // NO acquire fence: h is read via relaxed agent atomics (coherent by construction)
}

__global__ __launch_bounds__(256, 1) void lstm_persist(
    const float* __restrict__ seq, const u16* __restrict__ Wpack,
    const u16* __restrict__ Wdpack, const float* __restrict__ biasg,
    u16* __restrict__ hb0, u16* __restrict__ hb1,
    unsigned* __restrict__ flags, float* __restrict__ out) {
  __shared__ u16 hstage[2][32 * HSTR];   // 99,328 B: h_{s-1} tile, double-buffered
  __shared__ float gbuf[4][32 * GSTR];   // 51,200 B: per-wave gate partials
  __shared__ u16 xlds[32 * XSTR];        // 10,752 B: x_s tile (bf16, zero-padded K)
  __shared__ float biasl[96];            //     384 B      -> total 161,664 B: 1 WG/CU

  const int tid = threadIdx.x;
  const int w = tid >> 6;
  const int lane = tid & 63;
  const int l5 = lane & 31;
  const int hi = lane >> 5;
  const int bid = blockIdx.x;
  const int bt = bid >> 5;               // 0..7  batch tile (32 rows)
  const int ct = bid & 31;               // 0..31 h-col tile (24 h-cols / 96 gate-cols)
  const int b0 = bt * 32;
  unsigned* fl = flags + bt * 32;

  // one-time LDS init
  for (int i = tid; i < 32 * 31; i += 256) {      // zero x pad cols 129..159
    int r = i / 31, d = INDIM + i - r * 31;
    xlds[r * XSTR + d] = (u16)0;
  }
  if (tid < 96) biasl[tid] = biasg[(tid / 24) * HID + ct * 24 + (tid % 24)];

  // ---- recurrent-B fragments in registers: Breg[nt][t], wave w owns rec ksteps w*12..w*12+11 ----
  bf16x8 Breg[3][12];
  #pragma unroll
  for (int t = 0; t < 12; ++t)
    #pragma unroll
    for (int nt = 0; nt < 3; ++nt)
      Breg[nt][t] = *(const bf16x8*)(Wpack +
          (((size_t)(ct * 3 + nt)) * KS_TOT + (w * 12 + t)) * 512 + (size_t)lane * 8);

  const int icnt = (w < 2) ? 3 : 2;              // input ksteps: 3/3/2/2
  const int ioff = (w <= 2) ? w * 3 : 8;

  // cell state: thread-private (threads 0..191 own (row=tid/6, colgrp=tid%6) forever)
  float creg[4] = {0.f, 0.f, 0.f, 0.f};
  const int cr = tid / 6, cg = tid - (tid / 6) * 6;

  for (int s = 0; s < TT; ++s) {
    const u16* hbprev = (s & 1) ? hb1 : hb0;
    u16* hbnext       = (s & 1) ? hb0 : hb1;

    // ---- stage x_s (independent of h; overlaps with flag wait) ----
    {
      const float* xs = seq + ((size_t)s * BB + b0) * INDIM;
      for (int i = tid; i < 32 * INDIM; i += 256) {
        int r = i / INDIM, d = i - r * INDIM;
        xlds[r * XSTR + d] = f2bf(xs[i]);
      }
    }
    waitflags(fl, (unsigned)s, lane);
    // ---- stage h_{s-1} -> LDS via relaxed agent-atomic u64 (24 independent loads/thread) ----
    {
      const u64* hq = (const u64*)hbprev;
      u16* hd = hstage[s & 1];
      for (int i = tid; i < 6144; i += 256) {
        int r = i / 192, c4 = i - r * 192;
        u64 v = __hip_atomic_load(hq + (size_t)(b0 + r) * 192 + c4,
                                  __ATOMIC_RELAXED, __HIP_MEMORY_SCOPE_AGENT);
        *(u64*)&hd[r * HSTR + c4 * 4] = v;
      }
    }
    __syncthreads();   // B1: hstage + xlds ready

    // ---- gates: this wave's K-chunk, B from regs (rec) / L2 (input) ----
    {
      f32x16 acc[3] = {ZERO16, ZERO16, ZERO16};
      const u16* hs = hstage[s & 1];
      #pragma unroll
      for (int t = 0; t < 12; ++t) {
        bf16x8 a = *(const bf16x8*)(hs + l5 * HSTR + (w * 12 + t) * 16 + hi * 8);
        acc[0] = MFMA32(a, Breg[0][t], acc[0]);
        acc[1] = MFMA32(a, Breg[1][t], acc[1]);
        acc[2] = MFMA32(a, Breg[2][t], acc[2]);
      }
      #pragma unroll
      for (int u = 0; u < 3; ++u)
        if (u < icnt) {
          int kk = ioff + u;
          bf16x8 a = *(const bf16x8*)(xlds + l5 * XSTR + kk * 16 + hi * 8);
          #pragma unroll
          for (int nt = 0; nt < 3; ++nt) {
            bf16x8 b = *(const bf16x8*)(Wpack +
                (((size_t)(ct * 3 + nt)) * KS_TOT + KS_REC + kk) * 512 + (size_t)lane * 8);
            acc[nt] = MFMA32(a, b, acc[nt]);
          }
        }
      float* gb = gbuf[w];
      #pragma unroll
      for (int nt = 0; nt < 3; ++nt)
        #pragma unroll
        for (int r = 0; r < 16; ++r) {
          int row = (r & 3) + 8 * (r >> 2) + 4 * hi;
          gb[row * GSTR + nt * 32 + l5] = acc[nt][r];
        }
    }
    __syncthreads();   // B2: partials ready

    // ---- cell update: threads 0..191, 4 cells each, c in registers ----
    if (tid < 192) {
      float gv4[4][4];
      #pragma unroll
      for (int g = 0; g < 4; ++g) {
        f32x4 v = *(f32x4*)&gbuf[0][cr * GSTR + g * 24 + cg * 4];
        #pragma unroll
        for (int w2 = 1; w2 < 4; ++w2)
          v += *(f32x4*)&gbuf[w2][cr * GSTR + g * 24 + cg * 4];
        #pragma unroll
        for (int e = 0; e < 4; ++e) gv4[g][e] = v[e] + biasl[g * 24 + cg * 4 + e];
      }
      u64 pack = 0;
      #pragma unroll
      for (int e = 0; e < 4; ++e) {
        float iv = sigm(gv4[0][e]), fv = sigm(gv4[1][e]);
        float gg = tanh_fast(gv4[2][e]), ov = sigm(gv4[3][e]);
        float cn = fv * creg[e] + iv * gg;
        creg[e] = cn;
        pack |= (u64)f2bf(ov * tanh_fast(cn)) << (16 * e);
      }
      __hip_atomic_store((u64*)hbnext + ((size_t)(b0 + cr) * HID + ct * 24 + cg * 4) / 4,
                         pack, __ATOMIC_RELAXED, __HIP_MEMORY_SCOPE_AGENT);
    }
    __syncthreads();   // B3: h stores drained (vmcnt0 before barrier)

    if (tid == 0)
      __hip_atomic_store(&fl[ct], (unsigned)(s + 1), __ATOMIC_RELEASE, __HIP_MEMORY_SCOPE_AGENT);

    // ---- fused decode of h_{s-1} -> out[s-257], rotating duty, fills sync slack ----
    if (s >= 257 && ((ct >> 2) == ((s - 257) & 7))) {
      const int ont = ct & 3;
      f32x16 acc = ZERO16;
      const u16* hs = hstage[s & 1];
      #pragma unroll
      for (int t = 0; t < 12; ++t) {
        int ks = w * 12 + t;
        bf16x8 a = *(const bf16x8*)(hs + l5 * HSTR + ks * 16 + hi * 8);
        bf16x8 b = *(const bf16x8*)(Wdpack + (((size_t)ont * 48 + ks) * 64 + lane) * 8);
        acc = MFMA32(a, b, acc);
      }
      float* ob = out + ((size_t)(s - 257) * BB + b0) * OUTD + ont * 32;
      #pragma unroll
      for (int r = 0; r < 16; ++r) {
        int row = (r & 3) + 8 * (r >> 2) + 4 * hi;
        atomicAdd(&ob[(size_t)row * OUTD + l5], acc[r]);
      }
    }
  }

  // ---- tail: decode h_511 -> out[255] (duty group 7, reads hb[0] directly) ----
  if ((ct >> 2) == 7) {
    waitflags(fl, (unsigned)TT, lane);
    const int ont = ct & 3;
    const u64* hq = (const u64*)hb0;
    f32x16 acc = ZERO16;
    #pragma unroll
    for (int t = 0; t < 12; ++t) {
      int ks = w * 12 + t;
      union { u64 q[2]; bf16x8 v; } a;
      size_t base = ((size_t)(b0 + l5) * HID + ks * 16 + hi * 8) / 4;
      a.q[0] = __hip_atomic_load(hq + base,     __ATOMIC_RELAXED, __HIP_MEMORY_SCOPE_AGENT);
      a.q[1] = __hip_atomic_load(hq + base + 1, __ATOMIC_RELAXED, __HIP_MEMORY_SCOPE_AGENT);
      bf16x8 b = *(const bf16x8*)(Wdpack + (((size_t)ont * 48 + ks) * 64 + lane) * 8);
      acc = MFMA32(a.v, b, acc);
    }
    float* ob = out + ((size_t)255 * BB + b0) * OUTD + ont * 32;
    #pragma unroll
    for (int r = 0; r < 16; ++r) {
      int row = (r & 3) + 8 * (r >> 2) + 4 * hi;
      atomicAdd(&ob[(size_t)row * OUTD + l5], acc[r]);
    }
  }
}

extern "C" void kernel_launch(void* const* d_in, const int* in_sizes, int n_in,
                              void* d_out, int out_size, void* d_ws, size_t ws_size,
                              hipStream_t stream) {
  (void)in_sizes; (void)n_in; (void)out_size; (void)ws_size;
  const float* seq   = (const float*)d_in[0];
  const float* W_ih  = (const float*)d_in[1];
  const float* W_hh  = (const float*)d_in[2];
  const float* b_ih  = (const float*)d_in[3];
  const float* b_hh  = (const float*)d_in[4];
  const float* W_dec = (const float*)d_in[5];
  const float* b_dec = (const float*)d_in[6];
  float* out = (float*)d_out;

  // workspace layout (~6.7 MB, all offsets 16B-aligned)
  u16* Wpack  = (u16*)d_ws;                         // 32*3*58*512 bf16 = 5,701,632 B
  u16* Wdpack = Wpack + 32 * 3 * KS_TOT * 512;      // 98,304 bf16
  u16* h0     = Wdpack + 4 * 48 * 512;              // 256*768 bf16
  u16* h1     = h0 + BB * HID;                      // 256*768 bf16
  float* biasg = (float*)(h1 + BB * HID);           // 3072 f32
  unsigned* flags = (unsigned*)(biasg + 4 * HID);   // 256 u32

  prep_kernel<<<2048, 256, 0, stream>>>(W_ih, W_hh, b_ih, b_hh, W_dec, b_dec,
                                        Wpack, Wdpack, biasg, h0, flags, out);
  lstm_persist<<<256, 256, 0, stream>>>(seq, Wpack, Wdpack, biasg,
                                        h0, h1, flags, out);
}

// Round 4
// 6435.937 us; speedup vs baseline: 3.2944x; 1.1731x over previous
//
#include <hip/hip_runtime.h>
#include <cstdint>
#include <cstddef>

// ---- problem constants ----
#define TT 512
#define BB 256
#define HID 768
#define INDIM 129
#define INPAD 160
#define OUTD 128
#define KS_TOT 58   // 48 recurrent + 10 input ksteps of 16
#define KS_REC 48
#define HSTR 776    // hstage row stride (bf16): 768+8, 16B-aligned rows
#define XSTR 168    // xlds row stride (bf16)
#define GSTR 100    // gbuf row stride (f32), 16B-aligned, conflict-light

typedef __attribute__((ext_vector_type(8))) short bf16x8;
typedef __attribute__((ext_vector_type(4))) float f32x4;
typedef __attribute__((ext_vector_type(16))) float f32x16;
typedef unsigned short u16;
typedef unsigned long long u64;

#define MFMA32(A, B, C) __builtin_amdgcn_mfma_f32_32x32x16_bf16(A, B, C, 0, 0, 0)
#define ZERO16 {0.f,0.f,0.f,0.f,0.f,0.f,0.f,0.f,0.f,0.f,0.f,0.f,0.f,0.f,0.f,0.f}

__device__ __forceinline__ u16 f2bf(float f) {
  union { float f; unsigned u; } v; v.f = f;
  unsigned u = v.u;
  u += 0x7fffu + ((u >> 16) & 1u);   // RNE
  return (u16)(u >> 16);
}
__device__ __forceinline__ float sigm(float x) { return 1.0f / (1.0f + __expf(-x)); }
__device__ __forceinline__ float tanh_fast(float x) { return 2.0f / (1.0f + __expf(-2.0f * x)) - 1.0f; }

// ---------------- prep ----------------
__global__ __launch_bounds__(256) void prep_kernel(
    const float* __restrict__ W_ih, const float* __restrict__ W_hh,
    const float* __restrict__ b_ih, const float* __restrict__ b_hh,
    const float* __restrict__ W_dec, const float* __restrict__ b_dec,
    u16* __restrict__ Wpack, u16* __restrict__ Wdpack,
    float* __restrict__ biasg, u16* __restrict__ h0,
    unsigned* __restrict__ flags, float* __restrict__ out) {
  const int stride = blockDim.x * gridDim.x;
  const int i0 = blockIdx.x * blockDim.x + threadIdx.x;

  // Wpack[ct][nt][ks][lane][8]: B-frag for mfma_32x32x16 (n=lane&31, k=(lane>>5)*8+jj)
  for (int i = i0; i < 32 * 3 * KS_TOT * 512; i += stride) {
    int jj = i & 7, lane = (i >> 3) & 63, r = i >> 9;
    int ks = r % KS_TOT; int r2 = r / KS_TOT;
    int nt = r2 % 3, ct = r2 / 3;
    int p = nt * 32 + (lane & 31);          // packed gate-col 0..95
    int g = p / 24, j = p - g * 24;
    int row = g * HID + ct * 24 + j;        // W gate-row
    int kh = (lane >> 5) * 8 + jj;
    float v;
    if (ks < KS_REC) v = W_hh[(size_t)row * HID + ks * 16 + kh];
    else { int d = (ks - KS_REC) * 16 + kh; v = (d < INDIM) ? W_ih[(size_t)row * INDIM + d] : 0.f; }
    Wpack[i] = f2bf(v);
  }
  // Wdpack[ont][ks][lane][8]
  for (int i = i0; i < 4 * 48 * 512; i += stride) {
    int jj = i & 7, lane = (i >> 3) & 63, r = i >> 9;
    int ks = r % 48, nt = r / 48;
    int orow = nt * 32 + (lane & 31);
    int k = ks * 16 + (lane >> 5) * 8 + jj;
    Wdpack[i] = f2bf(W_dec[(size_t)orow * HID + k]);
  }
  for (int i = i0; i < 4 * HID; i += stride) biasg[i] = b_ih[i] + b_hh[i];
  for (int i = i0; i < BB * HID; i += stride) h0[i] = (u16)0;
  for (int i = i0; i < 256; i += stride) flags[i] = 0u;
  // out pre-init with decoder bias (decode K-split accumulates via atomicAdd)
  for (int i = i0; i < 256 * BB * OUTD; i += stride) out[i] = b_dec[i & (OUTD - 1)];
}

// ---------------- persistent LSTM ----------------
__device__ __forceinline__ void waitflags(unsigned* fl, unsigned target, int lane) {
  for (;;) {
    unsigned v = __hip_atomic_load(&fl[lane & 31], __ATOMIC_RELAXED, __HIP_MEMORY_SCOPE_AGENT);
    if (__all((int)(v >= target))) break;
    __builtin_amdgcn_s_sleep(1);
  }
  // NO acquire fence: h is read via relaxed agent atomics (coherent by construction)
}

__global__ __launch_bounds__(256, 1) void lstm_persist(
    const float* __restrict__ seq, const u16* __restrict__ Wpack,
    const u16* __restrict__ Wdpack, const float* __restrict__ biasg,
    u16* __restrict__ hb0, u16* __restrict__ hb1,
    unsigned* __restrict__ flags, float* __restrict__ out) {
  __shared__ u16 hstage[2][32 * HSTR];   // 99,328 B: h_{s-1} tile, double-buffered
  __shared__ float gbuf[4][32 * GSTR];   // 51,200 B: per-wave gate partials
  __shared__ u16 xlds[32 * XSTR];        // 10,752 B: x_s tile (bf16, zero-padded K)
  __shared__ float biasl[96];            //     384 B      -> total 161,664 B: 1 WG/CU

  const int tid = threadIdx.x;
  const int w = tid >> 6;
  const int lane = tid & 63;
  const int l5 = lane & 31;
  const int hi = lane >> 5;
  const int bid = blockIdx.x;
  const int bt = bid >> 5;               // 0..7  batch tile (32 rows)
  const int ct = bid & 31;               // 0..31 h-col tile (24 h-cols / 96 gate-cols)
  const int b0 = bt * 32;
  unsigned* fl = flags + bt * 32;

  // one-time LDS init
  for (int i = tid; i < 32 * 31; i += 256) {      // zero x pad cols 129..159
    int r = i / 31, d = INDIM + i - r * 31;
    xlds[r * XSTR + d] = (u16)0;
  }
  if (tid < 96) biasl[tid] = biasg[(tid / 24) * HID + ct * 24 + (tid % 24)];

  // ---- recurrent-B fragments in registers: Breg[nt][t], wave w owns rec ksteps w*12..w*12+11 ----
  bf16x8 Breg[3][12];
  #pragma unroll
  for (int t = 0; t < 12; ++t)
    #pragma unroll
    for (int nt = 0; nt < 3; ++nt)
      Breg[nt][t] = *(const bf16x8*)(Wpack +
          (((size_t)(ct * 3 + nt)) * KS_TOT + (w * 12 + t)) * 512 + (size_t)lane * 8);

  const int icnt = (w < 2) ? 3 : 2;              // input ksteps: 3/3/2/2
  const int ioff = (w <= 2) ? w * 3 : 8;

  // cell state: thread-private (threads 0..191 own (row=tid/6, colgrp=tid%6) forever)
  float creg[4] = {0.f, 0.f, 0.f, 0.f};
  const int cr = tid / 6, cg = tid - (tid / 6) * 6;

  for (int s = 0; s < TT; ++s) {
    const u16* hbprev = (s & 1) ? hb1 : hb0;
    u16* hbnext       = (s & 1) ? hb0 : hb1;

    // ---- stage x_s (independent of h; overlaps with flag wait) ----
    {
      const float* xs = seq + ((size_t)s * BB + b0) * INDIM;
      for (int i = tid; i < 32 * INDIM; i += 256) {
        int r = i / INDIM, d = i - r * INDIM;
        xlds[r * XSTR + d] = f2bf(xs[i]);
      }
    }
    waitflags(fl, (unsigned)s, lane);
    // ---- stage h_{s-1} -> LDS via relaxed agent-atomic u64 (24 independent loads/thread) ----
    {
      const u64* hq = (const u64*)hbprev;
      u16* hd = hstage[s & 1];
      for (int i = tid; i < 6144; i += 256) {
        int r = i / 192, c4 = i - r * 192;
        u64 v = __hip_atomic_load(hq + (size_t)(b0 + r) * 192 + c4,
                                  __ATOMIC_RELAXED, __HIP_MEMORY_SCOPE_AGENT);
        *(u64*)&hd[r * HSTR + c4 * 4] = v;
      }
    }
    __syncthreads();   // B1: hstage + xlds ready

    // ---- gates: this wave's K-chunk, B from regs (rec) / L2 (input) ----
    {
      f32x16 acc[3] = {ZERO16, ZERO16, ZERO16};
      const u16* hs = hstage[s & 1];
      #pragma unroll
      for (int t = 0; t < 12; ++t) {
        bf16x8 a = *(const bf16x8*)(hs + l5 * HSTR + (w * 12 + t) * 16 + hi * 8);
        acc[0] = MFMA32(a, Breg[0][t], acc[0]);
        acc[1] = MFMA32(a, Breg[1][t], acc[1]);
        acc[2] = MFMA32(a, Breg[2][t], acc[2]);
      }
      #pragma unroll
      for (int u = 0; u < 3; ++u)
        if (u < icnt) {
          int kk = ioff + u;
          bf16x8 a = *(const bf16x8*)(xlds + l5 * XSTR + kk * 16 + hi * 8);
          #pragma unroll
          for (int nt = 0; nt < 3; ++nt) {
            bf16x8 b = *(const bf16x8*)(Wpack +
                (((size_t)(ct * 3 + nt)) * KS_TOT + KS_REC + kk) * 512 + (size_t)lane * 8);
            acc[nt] = MFMA32(a, b, acc[nt]);
          }
        }
      float* gb = gbuf[w];
      #pragma unroll
      for (int nt = 0; nt < 3; ++nt)
        #pragma unroll
        for (int r = 0; r < 16; ++r) {
          int row = (r & 3) + 8 * (r >> 2) + 4 * hi;
          gb[row * GSTR + nt * 32 + l5] = acc[nt][r];
        }
    }
    __syncthreads();   // B2: partials ready

    // ---- cell update: threads 0..191, 4 cells each, c in registers ----
    if (tid < 192) {
      float gv4[4][4];
      #pragma unroll
      for (int g = 0; g < 4; ++g) {
        f32x4 v = *(f32x4*)&gbuf[0][cr * GSTR + g * 24 + cg * 4];
        #pragma unroll
        for (int w2 = 1; w2 < 4; ++w2)
          v += *(f32x4*)&gbuf[w2][cr * GSTR + g * 24 + cg * 4];
        #pragma unroll
        for (int e = 0; e < 4; ++e) gv4[g][e] = v[e] + biasl[g * 24 + cg * 4 + e];
      }
      u64 pack = 0;
      #pragma unroll
      for (int e = 0; e < 4; ++e) {
        float iv = sigm(gv4[0][e]), fv = sigm(gv4[1][e]);
        float gg = tanh_fast(gv4[2][e]), ov = sigm(gv4[3][e]);
        float cn = fv * creg[e] + iv * gg;
        creg[e] = cn;
        pack |= (u64)f2bf(ov * tanh_fast(cn)) << (16 * e);
      }
      __hip_atomic_store((u64*)hbnext + ((size_t)(b0 + cr) * HID + ct * 24 + cg * 4) / 4,
                         pack, __ATOMIC_RELAXED, __HIP_MEMORY_SCOPE_AGENT);
    }
    __syncthreads();   // B3: compiler emits s_waitcnt vmcnt(0) before s_barrier:
                       // all h stores (sc1 write-through) are ACKED at the coherence
                       // point before any thread proceeds.

    // Flag store is RELAXED: ordering vs the h stores is provided by B3's
    // vmcnt(0) drain. RELEASE here would emit buffer_wbl2 (full L2 writeback
    // scan) per WG per step -- measured R3: 85% idle, 14.7 us/step.
    if (tid == 0)
      __hip_atomic_store(&fl[ct], (unsigned)(s + 1), __ATOMIC_RELAXED, __HIP_MEMORY_SCOPE_AGENT);

    // ---- fused decode of h_{s-1} -> out[s-257], rotating duty, fills sync slack ----
    if (s >= 257 && ((ct >> 2) == ((s - 257) & 7))) {
      const int ont = ct & 3;
      f32x16 acc = ZERO16;
      const u16* hs = hstage[s & 1];
      #pragma unroll
      for (int t = 0; t < 12; ++t) {
        int ks = w * 12 + t;
        bf16x8 a = *(const bf16x8*)(hs + l5 * HSTR + ks * 16 + hi * 8);
        bf16x8 b = *(const bf16x8*)(Wdpack + (((size_t)ont * 48 + ks) * 64 + lane) * 8);
        acc = MFMA32(a, b, acc);
      }
      float* ob = out + ((size_t)(s - 257) * BB + b0) * OUTD + ont * 32;
      #pragma unroll
      for (int r = 0; r < 16; ++r) {
        int row = (r & 3) + 8 * (r >> 2) + 4 * hi;
        atomicAdd(&ob[(size_t)row * OUTD + l5], acc[r]);
      }
    }
  }

  // ---- tail: decode h_511 -> out[255] (duty group 7, reads hb[0] directly) ----
  if ((ct >> 2) == 7) {
    waitflags(fl, (unsigned)TT, lane);
    const int ont = ct & 3;
    const u64* hq = (const u64*)hb0;
    f32x16 acc = ZERO16;
    #pragma unroll
    for (int t = 0; t < 12; ++t) {
      int ks = w * 12 + t;
      union { u64 q[2]; bf16x8 v; } a;
      size_t base = ((size_t)(b0 + l5) * HID + ks * 16 + hi * 8) / 4;
      a.q[0] = __hip_atomic_load(hq + base,     __ATOMIC_RELAXED, __HIP_MEMORY_SCOPE_AGENT);
      a.q[1] = __hip_atomic_load(hq + base + 1, __ATOMIC_RELAXED, __HIP_MEMORY_SCOPE_AGENT);
      bf16x8 b = *(const bf16x8*)(Wdpack + (((size_t)ont * 48 + ks) * 64 + lane) * 8);
      acc = MFMA32(a.v, b, acc);
    }
    float* ob = out + ((size_t)255 * BB + b0) * OUTD + ont * 32;
    #pragma unroll
    for (int r = 0; r < 16; ++r) {
      int row = (r & 3) + 8 * (r >> 2) + 4 * hi;
      atomicAdd(&ob[(size_t)row * OUTD + l5], acc[r]);
    }
  }
}

extern "C" void kernel_launch(void* const* d_in, const int* in_sizes, int n_in,
                              void* d_out, int out_size, void* d_ws, size_t ws_size,
                              hipStream_t stream) {
  (void)in_sizes; (void)n_in; (void)out_size; (void)ws_size;
  const float* seq   = (const float*)d_in[0];
  const float* W_ih  = (const float*)d_in[1];
  const float* W_hh  = (const float*)d_in[2];
  const float* b_ih  = (const float*)d_in[3];
  const float* b_hh  = (const float*)d_in[4];
  const float* W_dec = (const float*)d_in[5];
  const float* b_dec = (const float*)d_in[6];
  float* out = (float*)d_out;

  // workspace layout (~6.7 MB, all offsets 16B-aligned)
  u16* Wpack  = (u16*)d_ws;                         // 32*3*58*512 bf16 = 5,701,632 B
  u16* Wdpack = Wpack + 32 * 3 * KS_TOT * 512;      // 98,304 bf16
  u16* h0     = Wdpack + 4 * 48 * 512;              // 256*768 bf16
  u16* h1     = h0 + BB * HID;                      // 256*768 bf16
  float* biasg = (float*)(h1 + BB * HID);           // 3072 f32
  unsigned* flags = (unsigned*)(biasg + 4 * HID);   // 256 u32

  prep_kernel<<<2048, 256, 0, stream>>>(W_ih, W_hh, b_ih, b_hh, W_dec, b_dec,
                                        Wpack, Wdpack, biasg, h0, flags, out);
  lstm_persist<<<256, 256, 0, stream>>>(seq, Wpack, Wdpack, biasg,
                                        h0, h1, flags, out);
}